// Round 4
// baseline (1375.079 us; speedup 1.0000x reference)
//
#include <hip/hip_runtime.h>
#include <hip/hip_bf16.h>
#include <math.h>

typedef __hip_bfloat16 bf16;
typedef __bf16 bf16x8 __attribute__((ext_vector_type(8)));
typedef float f32x4 __attribute__((ext_vector_type(4)));

#define HH 56
#define WW 56
#define WSZ 7
#define SSH 3
#define NHEAD 12
#define CDIM 384
#define BBATCH 32
#define NTOK 49
#define NWIN 64
#define HIDD 1536
#define HD 32
#define NWTOT (BBATCH*NWIN)       /* 2048 windows */
#define MROWS (NWTOT*NTOK)        /* 100352 rows */
#define MQ (MROWS/4)              /* 25088 */
#define LTOT (HH*WW)
#define EPSLN 1e-5f
#define QSCALE 0.17677669529663687f
#define NEGBIG -1e30f

enum { M_QKV = 0, M_PROJ = 1, M_FC1 = 2, M_FC2 = 3 };

__device__ __forceinline__ void gload16(const void* g, void* l) {
    __builtin_amdgcn_global_load_lds(
        (const __attribute__((address_space(1))) void*)g,
        (__attribute__((address_space(3))) void*)l, 16, 0, 0);
}

__device__ __forceinline__ unsigned short bfbits(float v) {
    bf16 b = __float2bfloat16(v);
    return *reinterpret_cast<unsigned short*>(&b);
}

// ---------------------------------------------------------------------------
__global__ __launch_bounds__(256) void cvt_k(const float* __restrict__ src,
                                             bf16* __restrict__ dst, int n) {
    int i = blockIdx.x * 256 + threadIdx.x;
    if (i < n) dst[i] = __float2bfloat16(src[i]);
}

// bias+mask table: tbl[wi][h][n][m(pad64)] ; m>=49 -> -1e30 (softmax automask)
__global__ __launch_bounds__(256)
void tbl_k(const float* __restrict__ rpb, const int* __restrict__ relidx,
           const float* __restrict__ amask, float* __restrict__ tbl) {
    int idx = blockIdx.x * 256 + threadIdx.x;   // 64*12*64*64
    int m = idx & 63, n = (idx >> 6) & 63;
    int h = (idx >> 12) % NHEAD, wi = idx / (64 * 64 * NHEAD);
    float v;
    if (m >= NTOK) v = NEGBIG;
    else if (n >= NTOK) v = 0.f;
    else v = rpb[relidx[n * NTOK + m] * NHEAD + h] + amask[((long)wi * NTOK + n) * NTOK + m];
    tbl[idx] = v;
}

// x [B][L][C] fp32 -> xw [MROWS][C] bf16 with cyclic shift + window partition
__global__ __launch_bounds__(256) void gather_k(const float* __restrict__ x,
                                                bf16* __restrict__ xw) {
    int idx = blockIdx.x * 256 + threadIdx.x;
    int rr = idx / 96, c4 = (idx % 96) * 4;
    int w = rr / 49, ti = rr % 49;
    int b = w >> 6, wi = w & 63;
    int hy = (wi >> 3) * 7 + ti / 7;
    int hx = (wi & 7) * 7 + ti % 7;
    int sh = hy + SSH; if (sh >= HH) sh -= HH;
    int sw = hx + SSH; if (sw >= WW) sw -= WW;
    float4 v = *(const float4*)&x[((long)b * LTOT + sh * WW + sw) * CDIM + c4];
    bf16* o = &xw[(long)rr * CDIM + c4];
    o[0] = __float2bfloat16(v.x); o[1] = __float2bfloat16(v.y);
    o[2] = __float2bfloat16(v.z); o[3] = __float2bfloat16(v.w);
}

// ---------------------------------------------------------------------------
// MFMA GEMM, 2-phase double-buffered pipeline + XCD-chunked m-major dispatch.
// 1-D grid of ntm*NTN blocks. Each K-step: issue next tile's global_load_lds,
// compute current from LDS, ONE __syncthreads (implicit vmcnt0 drain covers
// both hazards). M_QKV writes q,k -> Outp [w][2][h][49][32], v -> Outp2
// transposed [w][h][32][64pad].
// ---------------------------------------------------------------------------
template<int MODE, int KDIM, int NTN>
__global__ __launch_bounds__(256)
void mgemm_k(const bf16* __restrict__ A, const bf16* __restrict__ Wt,
             const float* __restrict__ bias, void* __restrict__ Outp,
             void* __restrict__ Outp2)
{
    __shared__ bf16 As[2][128 * 64];
    __shared__ bf16 Bs[2][128 * 64];
    const int tid = threadIdx.x;
    const int wid = tid >> 6, lane = tid & 63;

    // bijective XCD-chunk swizzle (m204) over an m-major linearization:
    // consecutive gid share the A-panel -> same-XCD L2 serves A re-reads.
    const int nwg = gridDim.x;
    const int orig = blockIdx.x;
    const int q = nwg >> 3, r = nwg & 7;
    const int xcd = orig & 7, loc = orig >> 3;
    const int gid = (xcd < r ? xcd * (q + 1) : r * (q + 1) + (xcd - r) * q) + loc;
    const int m0 = (gid / NTN) * 128;
    const int n0 = (gid % NTN) * 128;

    const int srow = lane >> 3, sseg = lane & 7;
    const bf16* Ag = A + (long)(m0 + wid * 32 + srow) * KDIM + sseg * 8;
    const bf16* Wg = Wt + (long)(n0 + wid * 32 + srow) * KDIM + sseg * 8;

    const int wr = (wid >> 1) * 64, wc = (wid & 1) * 64;
    const int frow = lane & 15, fk = (lane >> 4) * 8;

    f32x4 acc[4][4] = {};

    auto STAGE = [&](int b, int kt) {
#pragma unroll
        for (int i = 0; i < 4; ++i) {
            gload16(Ag + (long)(i * 8) * KDIM + kt, &As[b][(wid * 32 + i * 8) * 64]);
            gload16(Wg + (long)(i * 8) * KDIM + kt, &Bs[b][(wid * 32 + i * 8) * 64]);
        }
    };

    const int nt = KDIM / 64;
    STAGE(0, 0);
    __syncthreads();                 // implicit vmcnt(0): buf0 ready
    int buf = 0;
    for (int t = 0; t < nt; ++t) {
        if (t + 1 < nt) STAGE(buf ^ 1, (t + 1) * 64);   // async loads overlap compute
#pragma unroll
        for (int kk = 0; kk < 2; ++kk) {
            bf16x8 af[4], bfr[4];
#pragma unroll
            for (int i = 0; i < 4; ++i) {
                af[i]  = *(const bf16x8*)&As[buf][(wr + i * 16 + frow) * 64 + kk * 32 + fk];
                bfr[i] = *(const bf16x8*)&Bs[buf][(wc + i * 16 + frow) * 64 + kk * 32 + fk];
            }
#pragma unroll
            for (int mi = 0; mi < 4; ++mi)
#pragma unroll
                for (int ni = 0; ni < 4; ++ni)
                    acc[mi][ni] = __builtin_amdgcn_mfma_f32_16x16x32_bf16(
                        af[mi], bfr[ni], acc[mi][ni], 0, 0, 0);
        }
        __syncthreads();             // drains vmcnt->0 (next buf ready) + lgkm (reads done)
        buf ^= 1;
    }

#pragma unroll
    for (int mi = 0; mi < 4; ++mi) {
#pragma unroll
        for (int ni = 0; ni < 4; ++ni) {
            const int n = n0 + wc + ni * 16 + frow;
            const float bn = bias[n];
#pragma unroll
            for (int j = 0; j < 4; ++j) {
                const int m = m0 + wr + mi * 16 + (lane >> 4) * 4 + j;
                float v = acc[mi][ni][j] + bn;
                if (MODE == M_QKV) {
                    int which = n / CDIM, nn = n % CDIM;
                    int head = nn >> 5, d = nn & 31;
                    int w = m / 49, ti = m % 49;
                    if (which == 2) {
                        ((bf16*)Outp2)[(((long)w * NHEAD + head) * HD + d) * 64 + ti]
                            = __float2bfloat16(v);
                    } else {
                        if (which == 0) v *= QSCALE;
                        ((bf16*)Outp)[((((long)w * 2 + which) * NHEAD + head) * NTOK + ti) * HD + d]
                            = __float2bfloat16(v);
                    }
                } else if (MODE == M_PROJ) {
                    int w = m / 49, ti = m % 49;
                    int b = w >> 6, wi = w & 63;
                    int hy = (wi >> 3) * 7 + ti / 7;
                    int hx = (wi & 7) * 7 + ti % 7;
                    int dh = hy + SSH; if (dh >= HH) dh -= HH;
                    int dw = hx + SSH; if (dw >= WW) dw -= WW;
                    ((bf16*)Outp)[((long)b * LTOT + dh * WW + dw) * CDIM + n]
                        = __float2bfloat16(v);
                } else if (MODE == M_FC1) {
                    float g = 0.5f * v * (1.0f + erff(v * 0.70710678118654752f));
                    ((bf16*)Outp)[(long)m * HIDD + n] = __float2bfloat16(g);
                } else {
                    ((bf16*)Outp)[(long)m * CDIM + n] = __float2bfloat16(v);
                }
            }
        }
    }
}

// ---------------------------------------------------------------------------
// MFMA attention: 4 waves/block, each wave = one (window, head).
// ---------------------------------------------------------------------------
__global__ __launch_bounds__(256)
void mattn_k(const bf16* __restrict__ qk, const bf16* __restrict__ vT,
             const float* __restrict__ tbl, bf16* __restrict__ attn_out)
{
    __shared__ bf16 Plds[4][64 * 72];
    const int tid = threadIdx.x, wid = tid >> 6, lane = tid & 63;
    const int t = blockIdx.x * 4 + wid;
    const int w = t / NHEAD, h = t % NHEAD, wi = w & 63;
    const int l15 = lane & 15, g = lane >> 4;
    const bf16* qb = qk + ((long)(w * 2 + 0) * NHEAD + h) * (NTOK * HD);
    const bf16* kb = qk + ((long)(w * 2 + 1) * NHEAD + h) * (NTOK * HD);
    const bf16* vt = vT + ((long)w * NHEAD + h) * (HD * 64);
    const float* Tb = tbl + (long)(wi * NHEAD + h) * 64 * 64;
    char* Pw = (char*)&Plds[wid][0];

    bf16x8 kf[4], qf[4];
#pragma unroll
    for (int i = 0; i < 4; ++i) {
        kf[i] = *(const bf16x8*)&kb[(16 * i + l15) * HD + 8 * g];
        qf[i] = *(const bf16x8*)&qb[(16 * i + l15) * HD + 8 * g];
    }
    f32x4 s[4][4] = {};
#pragma unroll
    for (int mi = 0; mi < 4; ++mi)
#pragma unroll
        for (int ni = 0; ni < 4; ++ni)
            s[mi][ni] = __builtin_amdgcn_mfma_f32_16x16x32_bf16(
                kf[mi], qf[ni], s[mi][ni], 0, 0, 0);

#pragma unroll
    for (int ni = 0; ni < 4; ++ni) {
        const int n = 16 * ni + l15;
#pragma unroll
        for (int mi = 0; mi < 4; ++mi) {
            float4 tv = *(const float4*)&Tb[(long)n * 64 + 16 * mi + 4 * g];
            s[mi][ni][0] += tv.x; s[mi][ni][1] += tv.y;
            s[mi][ni][2] += tv.z; s[mi][ni][3] += tv.w;
        }
        float mx = NEGBIG;
#pragma unroll
        for (int mi = 0; mi < 4; ++mi)
#pragma unroll
            for (int j = 0; j < 4; ++j) mx = fmaxf(mx, s[mi][ni][j]);
        mx = fmaxf(mx, __shfl_xor(mx, 16));
        mx = fmaxf(mx, __shfl_xor(mx, 32));
        float sum = 0.f;
#pragma unroll
        for (int mi = 0; mi < 4; ++mi)
#pragma unroll
            for (int j = 0; j < 4; ++j) {
                float e = expf(s[mi][ni][j] - mx);
                s[mi][ni][j] = e; sum += e;
            }
        sum += __shfl_xor(sum, 16);
        sum += __shfl_xor(sum, 32);
        const float r = 1.0f / sum;
#pragma unroll
        for (int mi = 0; mi < 4; ++mi) {
            ushort4 u;
            u.x = bfbits(s[mi][ni][0] * r);
            u.y = bfbits(s[mi][ni][1] * r);
            u.z = bfbits(s[mi][ni][2] * r);
            u.w = bfbits(s[mi][ni][3] * r);
            *(ushort4*)(Pw + (long)n * 144 + (16 * mi + 4 * g) * 2) = u;
        }
    }

    f32x4 o[4][2] = {};
#pragma unroll
    for (int kk = 0; kk < 2; ++kk) {
        bf16x8 vf[2];
        vf[0] = *(const bf16x8*)&vt[(long)(l15) * 64 + 32 * kk + 8 * g];
        vf[1] = *(const bf16x8*)&vt[(long)(16 + l15) * 64 + 32 * kk + 8 * g];
#pragma unroll
        for (int rt = 0; rt < 4; ++rt) {
            bf16x8 pf = *(const bf16x8*)(Pw + (long)(16 * rt + l15) * 144 + (32 * kk + 8 * g) * 2);
            o[rt][0] = __builtin_amdgcn_mfma_f32_16x16x32_bf16(pf, vf[0], o[rt][0], 0, 0, 0);
            o[rt][1] = __builtin_amdgcn_mfma_f32_16x16x32_bf16(pf, vf[1], o[rt][1], 0, 0, 0);
        }
    }

#pragma unroll
    for (int rt = 0; rt < 4; ++rt)
#pragma unroll
        for (int dt = 0; dt < 2; ++dt)
#pragma unroll
            for (int j = 0; j < 4; ++j) {
                int n = 16 * rt + 4 * g + j;
                if (n < NTOK)
                    attn_out[((long)w * NTOK + n) * CDIM + h * HD + 16 * dt + l15]
                        = __float2bfloat16(o[rt][dt][j]);
            }
}

// ---------------------------------------------------------------------------
__global__ __launch_bounds__(256)
void ln_add_k(const bf16* __restrict__ Yrow, const float* base,
              const float* __restrict__ g, const float* __restrict__ bta,
              float* outp, bf16* outb)
{
    const int wv = threadIdx.x >> 6, lane = threadIdx.x & 63;
    const long t = (long)blockIdx.x * 4 + wv;
    const bf16* yr = Yrow + t * CDIM;
    float vals[6];
    float s = 0.f;
#pragma unroll
    for (int i = 0; i < 6; ++i) { vals[i] = __bfloat162float(yr[lane + i * 64]); s += vals[i]; }
#pragma unroll
    for (int o = 32; o; o >>= 1) s += __shfl_xor(s, o);
    const float mean = s * (1.f / 384.f);
    float vsum = 0.f;
#pragma unroll
    for (int i = 0; i < 6; ++i) { float d = vals[i] - mean; vsum += d * d; }
#pragma unroll
    for (int o = 32; o; o >>= 1) vsum += __shfl_xor(vsum, o);
    const float rstd = rsqrtf(vsum * (1.f / 384.f) + EPSLN);
#pragma unroll
    for (int i = 0; i < 6; ++i) {
        int c = lane + i * 64;
        float r = base[t * CDIM + c] + (vals[i] - mean) * rstd * g[c] + bta[c];
        outp[t * CDIM + c] = r;
        if (outb) outb[t * CDIM + c] = __float2bfloat16(r);
    }
}

extern "C" void kernel_launch(void* const* d_in, const int* in_sizes, int n_in,
                              void* d_out, int out_size, void* d_ws, size_t ws_size,
                              hipStream_t stream)
{
    const float* x      = (const float*)d_in[0];
    const float* qkv_w  = (const float*)d_in[1];
    const float* qkv_b  = (const float*)d_in[2];
    const float* proj_w = (const float*)d_in[3];
    const float* proj_b = (const float*)d_in[4];
    const float* rpb    = (const float*)d_in[5];
    const float* ln1_g  = (const float*)d_in[6];
    const float* ln1_b  = (const float*)d_in[7];
    const float* fc1_w  = (const float*)d_in[8];
    const float* fc1_b  = (const float*)d_in[9];
    const float* fc2_w  = (const float*)d_in[10];
    const float* fc2_b  = (const float*)d_in[11];
    const float* ln2_g  = (const float*)d_in[12];
    const float* ln2_b  = (const float*)d_in[13];
    const float* amask  = (const float*)d_in[14];
    const int*   relidx = (const int*)d_in[15];
    float* out = (float*)d_out;
    char*  ws  = (char*)d_ws;

    // workspace layout (peak 347,996,160 B; 385,351,680 proven available in R1)
    bf16*  wq   = (bf16*) (ws + 0L);
    bf16*  wp   = (bf16*) (ws + 884736L);
    bf16*  w1   = (bf16*) (ws + 1179648L);
    bf16*  w2   = (bf16*) (ws + 2359296L);
    float* tbl  = (float*)(ws + 3538944L);      // 12,582,912
    bf16*  xw   = (bf16*) (ws + 16121856L);     // 77,070,336  (dead after QKV)
    bf16*  qkb  = (bf16*) (ws + 93192192L);     // 154,140,672 q,k (dead after attn)
    bf16*  vTb  = (bf16*) (ws + 247332864L);    // 100,663,296 v^T (dead after attn)
    bf16*  attn_o = (bf16*)(ws + 16121856L);    // reuses xw (dead after proj)
    bf16*  Pbuf = (bf16*) (ws + 93192192L);     // reuses qk (dead after LN1)
    bf16*  x1b  = (bf16*) (ws + 170262528L);    // reuses qk (dead after FC1s)
    bf16*  H1   = (bf16*) (ws + 247332864L);    // reuses vT (per FFN chunk)
    bf16*  Ybuf = (bf16*) (ws + 93192192L);     // reuses Pbuf (after LN1)

    dim3 blk(256);

    cvt_k<<<dim3((3*CDIM*CDIM + 255)/256), blk, 0, stream>>>(qkv_w, wq, 3*CDIM*CDIM);
    cvt_k<<<dim3((CDIM*CDIM + 255)/256), blk, 0, stream>>>(proj_w, wp, CDIM*CDIM);
    cvt_k<<<dim3((HIDD*CDIM + 255)/256), blk, 0, stream>>>(fc1_w, w1, HIDD*CDIM);
    cvt_k<<<dim3((CDIM*HIDD + 255)/256), blk, 0, stream>>>(fc2_w, w2, CDIM*HIDD);
    tbl_k<<<dim3(64*12*64*64/256), blk, 0, stream>>>(rpb, relidx, amask, tbl);
    gather_k<<<dim3(MROWS * 96 / 256), blk, 0, stream>>>(x, xw);

    // 1. QKV projection (q,k normal; v transposed)   grid = 784*9
    mgemm_k<M_QKV, CDIM, 9><<<dim3((MROWS/128)*9), blk, 0, stream>>>(
        xw, wq, qkv_b, (void*)qkb, (void*)vTb);

    // 2. MFMA windowed attention
    mattn_k<<<dim3(NWTOT * NHEAD / 4), blk, 0, stream>>>(qkb, vTb, tbl, attn_o);

    // 3. output projection (fused window-reverse scatter)  grid = 784*3
    mgemm_k<M_PROJ, CDIM, 3><<<dim3((MROWS/128)*3), blk, 0, stream>>>(
        attn_o, wp, proj_b, (void*)Pbuf, nullptr);

    // 4. x1 = x + LN1(P) -> d_out fp32 + bf16 copy
    ln_add_k<<<dim3(MROWS/4), blk, 0, stream>>>(Pbuf, x, ln1_g, ln1_b, out, x1b);

    // 5/6. FFN in four M-chunks (H1 chunk fits freed vT region)
    for (int c = 0; c < 4; ++c) {
        const bf16* a1 = x1b + (long)c * MQ * CDIM;
        bf16* yc = Ybuf + (long)c * MQ * CDIM;
        mgemm_k<M_FC1, CDIM, 12><<<dim3((MQ/128)*12), blk, 0, stream>>>(
            a1, w1, fc1_b, (void*)H1, nullptr);
        mgemm_k<M_FC2, HIDD, 3><<<dim3((MQ/128)*3), blk, 0, stream>>>(
            H1, w2, fc2_b, (void*)yc, nullptr);
    }

    // 7. out = x1 + LN2(y)  (in-place)
    ln_add_k<<<dim3(MROWS/4), blk, 0, stream>>>(Ybuf, out, ln2_g, ln2_b, out, nullptr);
}

// Round 5
// 1162.391 us; speedup vs baseline: 1.1830x; 1.1830x over previous
//
#include <hip/hip_runtime.h>
#include <hip/hip_bf16.h>
#include <math.h>

typedef __hip_bfloat16 bf16;
typedef __bf16 bf16x8 __attribute__((ext_vector_type(8)));
typedef float f32x4 __attribute__((ext_vector_type(4)));

#define HH 56
#define WW 56
#define WSZ 7
#define SSH 3
#define NHEAD 12
#define CDIM 384
#define BBATCH 32
#define NTOK 49
#define NWIN 64
#define HIDD 1536
#define HD 32
#define NWTOT (BBATCH*NWIN)       /* 2048 windows */
#define MROWS (NWTOT*NTOK)        /* 100352 rows */
#define MQ (MROWS/4)              /* 25088 */
#define LTOT (HH*WW)
#define EPSLN 1e-5f
#define QSCALE 0.17677669529663687f
#define NEGBIG -1e30f

enum { M_QKV = 0, M_PROJ = 1, M_FC1 = 2, M_FC2 = 3 };

__device__ __forceinline__ void gload16(const void* g, void* l) {
    __builtin_amdgcn_global_load_lds(
        (const __attribute__((address_space(1))) void*)g,
        (__attribute__((address_space(3))) void*)l, 16, 0, 0);
}

__device__ __forceinline__ unsigned short bfbits(float v) {
    bf16 b = __float2bfloat16(v);
    return *reinterpret_cast<unsigned short*>(&b);
}

// ---------------------------------------------------------------------------
__global__ __launch_bounds__(256) void cvt_k(const float* __restrict__ src,
                                             bf16* __restrict__ dst, int n) {
    int i = blockIdx.x * 256 + threadIdx.x;
    if (i < n) dst[i] = __float2bfloat16(src[i]);
}

// bias+mask table: tbl[wi][h][n][m(pad64)] ; m>=49 -> -1e30 (softmax automask)
__global__ __launch_bounds__(256)
void tbl_k(const float* __restrict__ rpb, const int* __restrict__ relidx,
           const float* __restrict__ amask, float* __restrict__ tbl) {
    int idx = blockIdx.x * 256 + threadIdx.x;   // 64*12*64*64
    int m = idx & 63, n = (idx >> 6) & 63;
    int h = (idx >> 12) % NHEAD, wi = idx / (64 * 64 * NHEAD);
    float v;
    if (m >= NTOK) v = NEGBIG;
    else if (n >= NTOK) v = 0.f;
    else v = rpb[relidx[n * NTOK + m] * NHEAD + h] + amask[((long)wi * NTOK + n) * NTOK + m];
    tbl[idx] = v;
}

// x [B][L][C] fp32 -> xw [MROWS][C] bf16 with cyclic shift + window partition
__global__ __launch_bounds__(256) void gather_k(const float* __restrict__ x,
                                                bf16* __restrict__ xw) {
    int idx = blockIdx.x * 256 + threadIdx.x;
    int rr = idx / 96, c4 = (idx % 96) * 4;
    int w = rr / 49, ti = rr % 49;
    int b = w >> 6, wi = w & 63;
    int hy = (wi >> 3) * 7 + ti / 7;
    int hx = (wi & 7) * 7 + ti % 7;
    int sh = hy + SSH; if (sh >= HH) sh -= HH;
    int sw = hx + SSH; if (sw >= WW) sw -= WW;
    float4 v = *(const float4*)&x[((long)b * LTOT + sh * WW + sw) * CDIM + c4];
    bf16* o = &xw[(long)rr * CDIM + c4];
    o[0] = __float2bfloat16(v.x); o[1] = __float2bfloat16(v.y);
    o[2] = __float2bfloat16(v.z); o[3] = __float2bfloat16(v.w);
}

// ---------------------------------------------------------------------------
// MFMA GEMM. 128x128 tile, BK=64, 4 waves. Counted-vmcnt double-buffered
// pipeline (no vmcnt(0) drain in main loop) + T2 both-sides LDS swizzle
// (linear global_load_lds dest, pre-swizzled per-lane GLOBAL source seg,
// XOR on ds_read address) + XCD-chunked m-major dispatch (bijective, m204).
// ---------------------------------------------------------------------------
template<int MODE, int KDIM, int NTN>
__global__ __launch_bounds__(256)
void mgemm_k(const bf16* __restrict__ A, const bf16* __restrict__ Wt,
             const float* __restrict__ bias, void* __restrict__ Outp,
             void* __restrict__ Outp2)
{
    __shared__ bf16 As[2][128 * 64];
    __shared__ bf16 Bs[2][128 * 64];
    const int tid = threadIdx.x;
    const int wid = tid >> 6, lane = tid & 63;

    const int nwg = gridDim.x;
    const int orig = blockIdx.x;
    const int q = nwg >> 3, r = nwg & 7;
    const int xcd = orig & 7, loc = orig >> 3;
    const int gid = (xcd < r ? xcd * (q + 1) : r * (q + 1) + (xcd - r) * q) + loc;
    const int m0 = (gid / NTN) * 128;
    const int n0 = (gid % NTN) * 128;

    // staging geometry: wave covers rows [wid*32, wid*32+32), lane -> row
    // (srow within 8-row group) and 16B segment sseg. LDS layout is the
    // XOR-swizzled image: LDS slot (row, s) holds global seg s ^ (row&7),
    // achieved by pre-swizzling the GLOBAL source (dest stays linear).
    const int srow = lane >> 3, sseg = lane & 7;
    const int swseg = sseg ^ (srow & 7);       // (i*8 rows don't change &7)
    const bf16* Ag = A + (long)(m0 + wid * 32 + srow) * KDIM + swseg * 8;
    const bf16* Wg = Wt + (long)(n0 + wid * 32 + srow) * KDIM + swseg * 8;

    const int wr = (wid >> 1) * 64, wc = (wid & 1) * 64;
    const int frow = lane & 15, g4 = lane >> 4;

    f32x4 acc[4][4] = {};

    auto STAGE = [&](int b, int t) {
#pragma unroll
        for (int i = 0; i < 4; ++i) {
            gload16(Ag + (long)(i * 8) * KDIM + t * 64, &As[b][(wid * 32 + i * 8) * 64]);
            gload16(Wg + (long)(i * 8) * KDIM + t * 64, &Bs[b][(wid * 32 + i * 8) * 64]);
        }
    };

    const int nt = KDIM / 64;   // >= 2 always (K=384 or 1536)
    STAGE(0, 0);
    STAGE(1, 1);
    asm volatile("s_waitcnt vmcnt(8)" ::: "memory");   // tile0's 8 loads landed
    __builtin_amdgcn_s_barrier();

    int buf = 0;
    for (int t = 0; t < nt; ++t) {
        // 1. LDS -> regs (swizzled read addresses)
        bf16x8 af[2][4], bfr[2][4];
#pragma unroll
        for (int kk = 0; kk < 2; ++kk)
#pragma unroll
            for (int i = 0; i < 4; ++i) {
                const int ra = wr + i * 16 + frow;
                const int rb = wc + i * 16 + frow;
                const int sa = (4 * kk + g4) ^ (ra & 7);
                const int sb = (4 * kk + g4) ^ (rb & 7);
                af[kk][i]  = *(const bf16x8*)&As[buf][ra * 64 + sa * 8];
                bfr[kk][i] = *(const bf16x8*)&Bs[buf][rb * 64 + sb * 8];
            }
        __builtin_amdgcn_sched_barrier(0);
        asm volatile("s_waitcnt lgkmcnt(0)" ::: "memory");  // reads complete
        __builtin_amdgcn_sched_barrier(0);
        __builtin_amdgcn_s_barrier();        // all waves done reading buf
        // 2. refill the just-freed buffer with tile t+2 (stays in flight)
        if (t + 2 < nt) STAGE(buf, t + 2);
        // 3. MFMA on registers
#pragma unroll
        for (int kk = 0; kk < 2; ++kk)
#pragma unroll
            for (int mi = 0; mi < 4; ++mi)
#pragma unroll
                for (int ni = 0; ni < 4; ++ni)
                    acc[mi][ni] = __builtin_amdgcn_mfma_f32_16x16x32_bf16(
                        af[kk][mi], bfr[kk][ni], acc[mi][ni], 0, 0, 0);
        // 4. counted wait: tile t+1's 8 loads done, t+2's 8 may stay in flight
        if (t + 2 < nt) { asm volatile("s_waitcnt vmcnt(8)" ::: "memory"); }
        else            { asm volatile("s_waitcnt vmcnt(0)" ::: "memory"); }
        __builtin_amdgcn_s_barrier();        // every wave passed its own wait
        buf ^= 1;
    }

#pragma unroll
    for (int mi = 0; mi < 4; ++mi) {
#pragma unroll
        for (int ni = 0; ni < 4; ++ni) {
            const int n = n0 + wc + ni * 16 + frow;
            const float bn = bias[n];
#pragma unroll
            for (int j = 0; j < 4; ++j) {
                const int m = m0 + wr + mi * 16 + (lane >> 4) * 4 + j;
                float v = acc[mi][ni][j] + bn;
                if (MODE == M_QKV) {
                    int which = n / CDIM, nn = n % CDIM;
                    int head = nn >> 5, d = nn & 31;
                    int w = m / 49, ti = m % 49;
                    if (which == 2) {
                        ((bf16*)Outp2)[(((long)w * NHEAD + head) * HD + d) * 64 + ti]
                            = __float2bfloat16(v);
                    } else {
                        if (which == 0) v *= QSCALE;
                        ((bf16*)Outp)[((((long)w * 2 + which) * NHEAD + head) * NTOK + ti) * HD + d]
                            = __float2bfloat16(v);
                    }
                } else if (MODE == M_PROJ) {
                    int w = m / 49, ti = m % 49;
                    int b = w >> 6, wi = w & 63;
                    int hy = (wi >> 3) * 7 + ti / 7;
                    int hx = (wi & 7) * 7 + ti % 7;
                    int dh = hy + SSH; if (dh >= HH) dh -= HH;
                    int dw = hx + SSH; if (dw >= WW) dw -= WW;
                    ((bf16*)Outp)[((long)b * LTOT + dh * WW + dw) * CDIM + n]
                        = __float2bfloat16(v);
                } else if (MODE == M_FC1) {
                    float g = 0.5f * v * (1.0f + erff(v * 0.70710678118654752f));
                    ((bf16*)Outp)[(long)m * HIDD + n] = __float2bfloat16(g);
                } else {
                    ((bf16*)Outp)[(long)m * CDIM + n] = __float2bfloat16(v);
                }
            }
        }
    }
}

// ---------------------------------------------------------------------------
// MFMA attention: 4 waves/block, each wave = one (window, head).
// ---------------------------------------------------------------------------
__global__ __launch_bounds__(256)
void mattn_k(const bf16* __restrict__ qk, const bf16* __restrict__ vT,
             const float* __restrict__ tbl, bf16* __restrict__ attn_out)
{
    __shared__ bf16 Plds[4][64 * 72];
    const int tid = threadIdx.x, wid = tid >> 6, lane = tid & 63;
    const int t = blockIdx.x * 4 + wid;
    const int w = t / NHEAD, h = t % NHEAD, wi = w & 63;
    const int l15 = lane & 15, g = lane >> 4;
    const bf16* qb = qk + ((long)(w * 2 + 0) * NHEAD + h) * (NTOK * HD);
    const bf16* kb = qk + ((long)(w * 2 + 1) * NHEAD + h) * (NTOK * HD);
    const bf16* vt = vT + ((long)w * NHEAD + h) * (HD * 64);
    const float* Tb = tbl + (long)(wi * NHEAD + h) * 64 * 64;
    char* Pw = (char*)&Plds[wid][0];

    bf16x8 kf[4], qf[4];
#pragma unroll
    for (int i = 0; i < 4; ++i) {
        kf[i] = *(const bf16x8*)&kb[(16 * i + l15) * HD + 8 * g];
        qf[i] = *(const bf16x8*)&qb[(16 * i + l15) * HD + 8 * g];
    }
    f32x4 s[4][4] = {};
#pragma unroll
    for (int mi = 0; mi < 4; ++mi)
#pragma unroll
        for (int ni = 0; ni < 4; ++ni)
            s[mi][ni] = __builtin_amdgcn_mfma_f32_16x16x32_bf16(
                kf[mi], qf[ni], s[mi][ni], 0, 0, 0);

#pragma unroll
    for (int ni = 0; ni < 4; ++ni) {
        const int n = 16 * ni + l15;
#pragma unroll
        for (int mi = 0; mi < 4; ++mi) {
            float4 tv = *(const float4*)&Tb[(long)n * 64 + 16 * mi + 4 * g];
            s[mi][ni][0] += tv.x; s[mi][ni][1] += tv.y;
            s[mi][ni][2] += tv.z; s[mi][ni][3] += tv.w;
        }
        float mx = NEGBIG;
#pragma unroll
        for (int mi = 0; mi < 4; ++mi)
#pragma unroll
            for (int j = 0; j < 4; ++j) mx = fmaxf(mx, s[mi][ni][j]);
        mx = fmaxf(mx, __shfl_xor(mx, 16));
        mx = fmaxf(mx, __shfl_xor(mx, 32));
        float sum = 0.f;
#pragma unroll
        for (int mi = 0; mi < 4; ++mi)
#pragma unroll
            for (int j = 0; j < 4; ++j) {
                float e = expf(s[mi][ni][j] - mx);
                s[mi][ni][j] = e; sum += e;
            }
        sum += __shfl_xor(sum, 16);
        sum += __shfl_xor(sum, 32);
        const float r = 1.0f / sum;
#pragma unroll
        for (int mi = 0; mi < 4; ++mi) {
            ushort4 u;
            u.x = bfbits(s[mi][ni][0] * r);
            u.y = bfbits(s[mi][ni][1] * r);
            u.z = bfbits(s[mi][ni][2] * r);
            u.w = bfbits(s[mi][ni][3] * r);
            *(ushort4*)(Pw + (long)n * 144 + (16 * mi + 4 * g) * 2) = u;
        }
    }

    f32x4 o[4][2] = {};
#pragma unroll
    for (int kk = 0; kk < 2; ++kk) {
        bf16x8 vf[2];
        vf[0] = *(const bf16x8*)&vt[(long)(l15) * 64 + 32 * kk + 8 * g];
        vf[1] = *(const bf16x8*)&vt[(long)(16 + l15) * 64 + 32 * kk + 8 * g];
#pragma unroll
        for (int rt = 0; rt < 4; ++rt) {
            bf16x8 pf = *(const bf16x8*)(Pw + (long)(16 * rt + l15) * 144 + (32 * kk + 8 * g) * 2);
            o[rt][0] = __builtin_amdgcn_mfma_f32_16x16x32_bf16(pf, vf[0], o[rt][0], 0, 0, 0);
            o[rt][1] = __builtin_amdgcn_mfma_f32_16x16x32_bf16(pf, vf[1], o[rt][1], 0, 0, 0);
        }
    }

#pragma unroll
    for (int rt = 0; rt < 4; ++rt)
#pragma unroll
        for (int dt = 0; dt < 2; ++dt)
#pragma unroll
            for (int j = 0; j < 4; ++j) {
                int n = 16 * rt + 4 * g + j;
                if (n < NTOK)
                    attn_out[((long)w * NTOK + n) * CDIM + h * HD + 16 * dt + l15]
                        = __float2bfloat16(o[rt][dt][j]);
            }
}

// ---------------------------------------------------------------------------
__global__ __launch_bounds__(256)
void ln_add_k(const bf16* __restrict__ Yrow, const float* base,
              const float* __restrict__ g, const float* __restrict__ bta,
              float* outp, bf16* outb)
{
    const int wv = threadIdx.x >> 6, lane = threadIdx.x & 63;
    const long t = (long)blockIdx.x * 4 + wv;
    const bf16* yr = Yrow + t * CDIM;
    float vals[6];
    float s = 0.f;
#pragma unroll
    for (int i = 0; i < 6; ++i) { vals[i] = __bfloat162float(yr[lane + i * 64]); s += vals[i]; }
#pragma unroll
    for (int o = 32; o; o >>= 1) s += __shfl_xor(s, o);
    const float mean = s * (1.f / 384.f);
    float vsum = 0.f;
#pragma unroll
    for (int i = 0; i < 6; ++i) { float d = vals[i] - mean; vsum += d * d; }
#pragma unroll
    for (int o = 32; o; o >>= 1) vsum += __shfl_xor(vsum, o);
    const float rstd = rsqrtf(vsum * (1.f / 384.f) + EPSLN);
#pragma unroll
    for (int i = 0; i < 6; ++i) {
        int c = lane + i * 64;
        float r = base[t * CDIM + c] + (vals[i] - mean) * rstd * g[c] + bta[c];
        outp[t * CDIM + c] = r;
        if (outb) outb[t * CDIM + c] = __float2bfloat16(r);
    }
}

extern "C" void kernel_launch(void* const* d_in, const int* in_sizes, int n_in,
                              void* d_out, int out_size, void* d_ws, size_t ws_size,
                              hipStream_t stream)
{
    const float* x      = (const float*)d_in[0];
    const float* qkv_w  = (const float*)d_in[1];
    const float* qkv_b  = (const float*)d_in[2];
    const float* proj_w = (const float*)d_in[3];
    const float* proj_b = (const float*)d_in[4];
    const float* rpb    = (const float*)d_in[5];
    const float* ln1_g  = (const float*)d_in[6];
    const float* ln1_b  = (const float*)d_in[7];
    const float* fc1_w  = (const float*)d_in[8];
    const float* fc1_b  = (const float*)d_in[9];
    const float* fc2_w  = (const float*)d_in[10];
    const float* fc2_b  = (const float*)d_in[11];
    const float* ln2_g  = (const float*)d_in[12];
    const float* ln2_b  = (const float*)d_in[13];
    const float* amask  = (const float*)d_in[14];
    const int*   relidx = (const int*)d_in[15];
    float* out = (float*)d_out;
    char*  ws  = (char*)d_ws;

    // workspace layout (peak 347,996,160 B; 385,351,680 proven available in R1)
    bf16*  wq   = (bf16*) (ws + 0L);
    bf16*  wp   = (bf16*) (ws + 884736L);
    bf16*  w1   = (bf16*) (ws + 1179648L);
    bf16*  w2   = (bf16*) (ws + 2359296L);
    float* tbl  = (float*)(ws + 3538944L);      // 12,582,912
    bf16*  xw   = (bf16*) (ws + 16121856L);     // 77,070,336  (dead after QKV)
    bf16*  qkb  = (bf16*) (ws + 93192192L);     // 154,140,672 q,k (dead after attn)
    bf16*  vTb  = (bf16*) (ws + 247332864L);    // 100,663,296 v^T (dead after attn)
    bf16*  attn_o = (bf16*)(ws + 16121856L);    // reuses xw (dead after proj)
    bf16*  Pbuf = (bf16*) (ws + 93192192L);     // reuses qk (dead after LN1)
    bf16*  x1b  = (bf16*) (ws + 170262528L);    // reuses qk (dead after FC1s)
    bf16*  H1   = (bf16*) (ws + 247332864L);    // reuses vT (per FFN chunk)
    bf16*  Ybuf = (bf16*) (ws + 93192192L);     // reuses Pbuf (after LN1)

    dim3 blk(256);

    cvt_k<<<dim3((3*CDIM*CDIM + 255)/256), blk, 0, stream>>>(qkv_w, wq, 3*CDIM*CDIM);
    cvt_k<<<dim3((CDIM*CDIM + 255)/256), blk, 0, stream>>>(proj_w, wp, CDIM*CDIM);
    cvt_k<<<dim3((HIDD*CDIM + 255)/256), blk, 0, stream>>>(fc1_w, w1, HIDD*CDIM);
    cvt_k<<<dim3((CDIM*HIDD + 255)/256), blk, 0, stream>>>(fc2_w, w2, CDIM*HIDD);
    tbl_k<<<dim3(64*12*64*64/256), blk, 0, stream>>>(rpb, relidx, amask, tbl);
    gather_k<<<dim3(MROWS * 96 / 256), blk, 0, stream>>>(x, xw);

    // 1. QKV projection (q,k normal; v transposed)   grid = 784*9
    mgemm_k<M_QKV, CDIM, 9><<<dim3((MROWS/128)*9), blk, 0, stream>>>(
        xw, wq, qkv_b, (void*)qkb, (void*)vTb);

    // 2. MFMA windowed attention
    mattn_k<<<dim3(NWTOT * NHEAD / 4), blk, 0, stream>>>(qkb, vTb, tbl, attn_o);

    // 3. output projection (fused window-reverse scatter)  grid = 784*3
    mgemm_k<M_PROJ, CDIM, 3><<<dim3((MROWS/128)*3), blk, 0, stream>>>(
        attn_o, wp, proj_b, (void*)Pbuf, nullptr);

    // 4. x1 = x + LN1(P) -> d_out fp32 + bf16 copy
    ln_add_k<<<dim3(MROWS/4), blk, 0, stream>>>(Pbuf, x, ln1_g, ln1_b, out, x1b);

    // 5/6. FFN in four M-chunks (H1 chunk fits freed vT region)
    for (int c = 0; c < 4; ++c) {
        const bf16* a1 = x1b + (long)c * MQ * CDIM;
        bf16* yc = Ybuf + (long)c * MQ * CDIM;
        mgemm_k<M_FC1, CDIM, 12><<<dim3((MQ/128)*12), blk, 0, stream>>>(
            a1, w1, fc1_b, (void*)H1, nullptr);
        mgemm_k<M_FC2, HIDD, 3><<<dim3((MQ/128)*3), blk, 0, stream>>>(
            H1, w2, fc2_b, (void*)yc, nullptr);
    }

    // 7. out = x1 + LN2(y)  (in-place)
    ln_add_k<<<dim3(MROWS/4), blk, 0, stream>>>(Ybuf, out, ln2_g, ln2_b, out, nullptr);
}

// Round 6
// 1136.909 us; speedup vs baseline: 1.2095x; 1.0224x over previous
//
#include <hip/hip_runtime.h>
#include <hip/hip_bf16.h>
#include <math.h>

typedef __hip_bfloat16 bf16;
typedef __bf16 bf16x8 __attribute__((ext_vector_type(8)));
typedef float f32x4 __attribute__((ext_vector_type(4)));

#define HH 56
#define WW 56
#define WSZ 7
#define SSH 3
#define NHEAD 12
#define CDIM 384
#define BBATCH 32
#define NTOK 49
#define NWIN 64
#define HIDD 1536
#define HD 32
#define NWTOT (BBATCH*NWIN)       /* 2048 windows */
#define MROWS (NWTOT*NTOK)        /* 100352 rows */
#define MQ (MROWS/4)              /* 25088 */
#define LTOT (HH*WW)
#define EPSLN 1e-5f
#define QSCALE 0.17677669529663687f
#define NEGBIG -1e30f

enum { M_QK = 0, M_V = 1, M_PROJ = 2, M_FC1 = 3, M_FC2 = 4 };

__device__ __forceinline__ void gload16(const void* g, void* l) {
    __builtin_amdgcn_global_load_lds(
        (const __attribute__((address_space(1))) void*)g,
        (__attribute__((address_space(3))) void*)l, 16, 0, 0);
}

__device__ __forceinline__ unsigned short bfbits(float v) {
    bf16 b = __float2bfloat16(v);
    return *reinterpret_cast<unsigned short*>(&b);
}

// ---------------------------------------------------------------------------
__global__ __launch_bounds__(256) void cvt_k(const float* __restrict__ src,
                                             bf16* __restrict__ dst, int n) {
    int i = blockIdx.x * 256 + threadIdx.x;
    if (i < n) dst[i] = __float2bfloat16(src[i]);
}

// bias+mask table: tbl[wi][h][n][m(pad64)] ; m>=49 -> -1e30 (softmax automask)
__global__ __launch_bounds__(256)
void tbl_k(const float* __restrict__ rpb, const int* __restrict__ relidx,
           const float* __restrict__ amask, float* __restrict__ tbl) {
    int idx = blockIdx.x * 256 + threadIdx.x;   // 64*12*64*64
    int m = idx & 63, n = (idx >> 6) & 63;
    int h = (idx >> 12) % NHEAD, wi = idx / (64 * 64 * NHEAD);
    float v;
    if (m >= NTOK) v = NEGBIG;
    else if (n >= NTOK) v = 0.f;
    else v = rpb[relidx[n * NTOK + m] * NHEAD + h] + amask[((long)wi * NTOK + n) * NTOK + m];
    tbl[idx] = v;
}

// x [B][L][C] fp32 -> xw [MROWS][C] bf16 with cyclic shift + window partition
__global__ __launch_bounds__(256) void gather_k(const float* __restrict__ x,
                                                bf16* __restrict__ xw) {
    int idx = blockIdx.x * 256 + threadIdx.x;
    int rr = idx / 96, c4 = (idx % 96) * 4;
    int w = rr / 49, ti = rr % 49;
    int b = w >> 6, wi = w & 63;
    int hy = (wi >> 3) * 7 + ti / 7;
    int hx = (wi & 7) * 7 + ti % 7;
    int sh = hy + SSH; if (sh >= HH) sh -= HH;
    int sw = hx + SSH; if (sw >= WW) sw -= WW;
    float4 v = *(const float4*)&x[((long)b * LTOT + sh * WW + sw) * CDIM + c4];
    bf16* o = &xw[(long)rr * CDIM + c4];
    o[0] = __float2bfloat16(v.x); o[1] = __float2bfloat16(v.y);
    o[2] = __float2bfloat16(v.z); o[3] = __float2bfloat16(v.w);
}

// ---------------------------------------------------------------------------
// MFMA GEMM. 128x128 tile, BK=64, 4 waves, counted-vmcnt dbuf pipeline +
// T2 both-sides LDS swizzle + bijective XCD-chunk m-major dispatch.
// SWAP modes compute C^T fragments (mfma(b,a)): in-thread j runs along n ->
// ushort4 stores for n-contiguous dests. M_V keeps mfma(a,b): j along m=ti.
// ---------------------------------------------------------------------------
template<int MODE, int KDIM, int NTN>
__global__ __launch_bounds__(256)
void mgemm_k(const bf16* __restrict__ A, const bf16* __restrict__ Wt,
             const float* __restrict__ bias, void* __restrict__ Outp)
{
    constexpr bool SWAP = (MODE != M_V);
    __shared__ bf16 As[2][128 * 64];
    __shared__ bf16 Bs[2][128 * 64];
    const int tid = threadIdx.x;
    const int wid = tid >> 6, lane = tid & 63;

    const int nwg = gridDim.x;
    const int orig = blockIdx.x;
    const int q = nwg >> 3, r = nwg & 7;
    const int xcd = orig & 7, loc = orig >> 3;
    const int gid = (xcd < r ? xcd * (q + 1) : r * (q + 1) + (xcd - r) * q) + loc;
    const int m0 = (gid / NTN) * 128;
    const int n0 = (gid % NTN) * 128;

    const int srow = lane >> 3, sseg = lane & 7;
    const int swseg = sseg ^ (srow & 7);
    const bf16* Ag = A + (long)(m0 + wid * 32 + srow) * KDIM + swseg * 8;
    const bf16* Wg = Wt + (long)(n0 + wid * 32 + srow) * KDIM + swseg * 8;

    const int wr = (wid >> 1) * 64, wc = (wid & 1) * 64;
    const int l15 = lane & 15, g4 = lane >> 4;

    f32x4 acc[4][4] = {};

    auto STAGE = [&](int b, int t) {
#pragma unroll
        for (int i = 0; i < 4; ++i) {
            gload16(Ag + (long)(i * 8) * KDIM + t * 64, &As[b][(wid * 32 + i * 8) * 64]);
            gload16(Wg + (long)(i * 8) * KDIM + t * 64, &Bs[b][(wid * 32 + i * 8) * 64]);
        }
    };

    const int nt = KDIM / 64;
    STAGE(0, 0);
    STAGE(1, 1);
    asm volatile("s_waitcnt vmcnt(8)" ::: "memory");
    __builtin_amdgcn_s_barrier();

    int buf = 0;
    for (int t = 0; t < nt; ++t) {
        bf16x8 af[2][4], bfr[2][4];
#pragma unroll
        for (int kk = 0; kk < 2; ++kk)
#pragma unroll
            for (int i = 0; i < 4; ++i) {
                const int ra = wr + i * 16 + l15;
                const int rb = wc + i * 16 + l15;
                const int sa = (4 * kk + g4) ^ (ra & 7);
                const int sb = (4 * kk + g4) ^ (rb & 7);
                af[kk][i]  = *(const bf16x8*)&As[buf][ra * 64 + sa * 8];
                bfr[kk][i] = *(const bf16x8*)&Bs[buf][rb * 64 + sb * 8];
            }
        __builtin_amdgcn_sched_barrier(0);
        asm volatile("s_waitcnt lgkmcnt(0)" ::: "memory");
        __builtin_amdgcn_sched_barrier(0);
        __builtin_amdgcn_s_barrier();
        if (t + 2 < nt) STAGE(buf, t + 2);
#pragma unroll
        for (int kk = 0; kk < 2; ++kk)
#pragma unroll
            for (int mi = 0; mi < 4; ++mi)
#pragma unroll
                for (int ni = 0; ni < 4; ++ni) {
                    if (SWAP)
                        acc[ni][mi] = __builtin_amdgcn_mfma_f32_16x16x32_bf16(
                            bfr[kk][ni], af[kk][mi], acc[ni][mi], 0, 0, 0);
                    else
                        acc[mi][ni] = __builtin_amdgcn_mfma_f32_16x16x32_bf16(
                            af[kk][mi], bfr[kk][ni], acc[mi][ni], 0, 0, 0);
                }
        if (t + 2 < nt) { asm volatile("s_waitcnt vmcnt(8)" ::: "memory"); }
        else            { asm volatile("s_waitcnt vmcnt(0)" ::: "memory"); }
        __builtin_amdgcn_s_barrier();
        buf ^= 1;
    }

    // ---------------- epilogue ----------------
    if (MODE == M_V) {
        // acc[mi][ni][j]: m = m0+wr+mi*16+g4*4+j (ti dir), n = n0+wc+ni*16+l15
        // dest vT [w][h][d][64]: ushort4 along ti, split at window boundaries
#pragma unroll
        for (int mi = 0; mi < 4; ++mi) {
            const int mb = m0 + wr + mi * 16 + g4 * 4;
            const int wv_ = mb / 49, ti0 = mb - wv_ * 49;
#pragma unroll
            for (int ni = 0; ni < 4; ++ni) {
                const int n = n0 + wc + ni * 16 + l15;     // h*32+d
                const int h = n >> 5, d = n & 31;
                const float bn = bias[n];
                float v4[4];
#pragma unroll
                for (int j = 0; j < 4; ++j) v4[j] = acc[mi][ni][j] + bn;
                if (ti0 <= 45) {
                    ushort4 u = { bfbits(v4[0]), bfbits(v4[1]), bfbits(v4[2]), bfbits(v4[3]) };
                    *(ushort4*)&((bf16*)Outp)[(((long)wv_ * NHEAD + h) * HD + d) * 64 + ti0] = u;
                } else {
#pragma unroll
                    for (int j = 0; j < 4; ++j) {
                        const int m = mb + j;
                        const int w2 = m / 49, ti = m - w2 * 49;
                        ((bf16*)Outp)[(((long)w2 * NHEAD + h) * HD + d) * 64 + ti]
                            = __float2bfloat16(v4[j]);
                    }
                }
            }
        }
    } else {
        // acc[ni][mi][j]: n = n0+wc+ni*16+g4*4+j, m = m0+wr+mi*16+l15
        long rowbase[4];
        int wq_[4], ti_[4];
#pragma unroll
        for (int mi = 0; mi < 4; ++mi) {
            const int m = m0 + wr + mi * 16 + l15;
            if (MODE == M_QK) {
                wq_[mi] = m / 49; ti_[mi] = m - wq_[mi] * 49;
            } else if (MODE == M_PROJ) {
                int w = m / 49, ti = m - w * 49;
                int b = w >> 6, wi = w & 63;
                int hy = (wi >> 3) * 7 + ti / 7;
                int hx = (wi & 7) * 7 + ti % 7;
                int dh = hy + SSH; if (dh >= HH) dh -= HH;
                int dw = hx + SSH; if (dw >= WW) dw -= WW;
                rowbase[mi] = ((long)b * LTOT + dh * WW + dw) * CDIM;
            } else if (MODE == M_FC1) {
                rowbase[mi] = (long)m * HIDD;
            } else {
                rowbase[mi] = (long)m * CDIM;
            }
        }
#pragma unroll
        for (int ni = 0; ni < 4; ++ni) {
            const int nb = n0 + wc + ni * 16 + g4 * 4;
            const float4 bn = *(const float4*)&bias[nb];
            const float bb[4] = { bn.x, bn.y, bn.z, bn.w };
#pragma unroll
            for (int mi = 0; mi < 4; ++mi) {
                float v4[4];
#pragma unroll
                for (int j = 0; j < 4; ++j) v4[j] = acc[ni][mi][j] + bb[j];
                if (MODE == M_FC1) {
#pragma unroll
                    for (int j = 0; j < 4; ++j)
                        v4[j] = 0.5f * v4[j] * (1.0f + erff(v4[j] * 0.70710678118654752f));
                } else if (MODE == M_QK) {
                    if (nb < CDIM) {
#pragma unroll
                        for (int j = 0; j < 4; ++j) v4[j] *= QSCALE;
                    }
                }
                ushort4 u = { bfbits(v4[0]), bfbits(v4[1]), bfbits(v4[2]), bfbits(v4[3]) };
                if (MODE == M_QK) {
                    const int which = nb >= CDIM;
                    const int hb = (nb - which * CDIM) >> 5, d0 = nb & 31;
                    *(ushort4*)&((bf16*)Outp)[
                        ((((long)wq_[mi] * 2 + which) * NHEAD + hb) * NTOK + ti_[mi]) * HD + d0] = u;
                } else {
                    *(ushort4*)&((bf16*)Outp)[rowbase[mi] + nb] = u;
                }
            }
        }
    }
}

// ---------------------------------------------------------------------------
// MFMA attention: 4 waves/block, each wave = one (window, head). Unchanged.
// ---------------------------------------------------------------------------
__global__ __launch_bounds__(256)
void mattn_k(const bf16* __restrict__ qk, const bf16* __restrict__ vT,
             const float* __restrict__ tbl, bf16* __restrict__ attn_out)
{
    __shared__ bf16 Plds[4][64 * 72];
    const int tid = threadIdx.x, wid = tid >> 6, lane = tid & 63;
    const int t = blockIdx.x * 4 + wid;
    const int w = t / NHEAD, h = t % NHEAD, wi = w & 63;
    const int l15 = lane & 15, g = lane >> 4;
    const bf16* qb = qk + ((long)(w * 2 + 0) * NHEAD + h) * (NTOK * HD);
    const bf16* kb = qk + ((long)(w * 2 + 1) * NHEAD + h) * (NTOK * HD);
    const bf16* vt = vT + ((long)w * NHEAD + h) * (HD * 64);
    const float* Tb = tbl + (long)(wi * NHEAD + h) * 64 * 64;
    char* Pw = (char*)&Plds[wid][0];

    bf16x8 kf[4], qf[4];
#pragma unroll
    for (int i = 0; i < 4; ++i) {
        kf[i] = *(const bf16x8*)&kb[(16 * i + l15) * HD + 8 * g];
        qf[i] = *(const bf16x8*)&qb[(16 * i + l15) * HD + 8 * g];
    }
    f32x4 s[4][4] = {};
#pragma unroll
    for (int mi = 0; mi < 4; ++mi)
#pragma unroll
        for (int ni = 0; ni < 4; ++ni)
            s[mi][ni] = __builtin_amdgcn_mfma_f32_16x16x32_bf16(
                kf[mi], qf[ni], s[mi][ni], 0, 0, 0);

#pragma unroll
    for (int ni = 0; ni < 4; ++ni) {
        const int n = 16 * ni + l15;
#pragma unroll
        for (int mi = 0; mi < 4; ++mi) {
            float4 tv = *(const float4*)&Tb[(long)n * 64 + 16 * mi + 4 * g];
            s[mi][ni][0] += tv.x; s[mi][ni][1] += tv.y;
            s[mi][ni][2] += tv.z; s[mi][ni][3] += tv.w;
        }
        float mx = NEGBIG;
#pragma unroll
        for (int mi = 0; mi < 4; ++mi)
#pragma unroll
            for (int j = 0; j < 4; ++j) mx = fmaxf(mx, s[mi][ni][j]);
        mx = fmaxf(mx, __shfl_xor(mx, 16));
        mx = fmaxf(mx, __shfl_xor(mx, 32));
        float sum = 0.f;
#pragma unroll
        for (int mi = 0; mi < 4; ++mi)
#pragma unroll
            for (int j = 0; j < 4; ++j) {
                float e = expf(s[mi][ni][j] - mx);
                s[mi][ni][j] = e; sum += e;
            }
        sum += __shfl_xor(sum, 16);
        sum += __shfl_xor(sum, 32);
        const float r = 1.0f / sum;
#pragma unroll
        for (int mi = 0; mi < 4; ++mi) {
            ushort4 u;
            u.x = bfbits(s[mi][ni][0] * r);
            u.y = bfbits(s[mi][ni][1] * r);
            u.z = bfbits(s[mi][ni][2] * r);
            u.w = bfbits(s[mi][ni][3] * r);
            *(ushort4*)(Pw + (long)n * 144 + (16 * mi + 4 * g) * 2) = u;
        }
    }

    f32x4 o[4][2] = {};
#pragma unroll
    for (int kk = 0; kk < 2; ++kk) {
        bf16x8 vf[2];
        vf[0] = *(const bf16x8*)&vt[(long)(l15) * 64 + 32 * kk + 8 * g];
        vf[1] = *(const bf16x8*)&vt[(long)(16 + l15) * 64 + 32 * kk + 8 * g];
#pragma unroll
        for (int rt = 0; rt < 4; ++rt) {
            bf16x8 pf = *(const bf16x8*)(Pw + (long)(16 * rt + l15) * 144 + (32 * kk + 8 * g) * 2);
            o[rt][0] = __builtin_amdgcn_mfma_f32_16x16x32_bf16(pf, vf[0], o[rt][0], 0, 0, 0);
            o[rt][1] = __builtin_amdgcn_mfma_f32_16x16x32_bf16(pf, vf[1], o[rt][1], 0, 0, 0);
        }
    }

#pragma unroll
    for (int rt = 0; rt < 4; ++rt)
#pragma unroll
        for (int dt = 0; dt < 2; ++dt)
#pragma unroll
            for (int j = 0; j < 4; ++j) {
                int n = 16 * rt + 4 * g + j;
                if (n < NTOK)
                    attn_out[((long)w * NTOK + n) * CDIM + h * HD + 16 * dt + l15]
                        = __float2bfloat16(o[rt][dt][j]);
            }
}

// ---------------------------------------------------------------------------
__global__ __launch_bounds__(256)
void ln_add_k(const bf16* __restrict__ Yrow, const float* base,
              const float* __restrict__ g, const float* __restrict__ bta,
              float* outp, bf16* outb)
{
    const int wv = threadIdx.x >> 6, lane = threadIdx.x & 63;
    const long t = (long)blockIdx.x * 4 + wv;
    const bf16* yr = Yrow + t * CDIM;
    float vals[6];
    float s = 0.f;
#pragma unroll
    for (int i = 0; i < 6; ++i) { vals[i] = __bfloat162float(yr[lane + i * 64]); s += vals[i]; }
#pragma unroll
    for (int o = 32; o; o >>= 1) s += __shfl_xor(s, o);
    const float mean = s * (1.f / 384.f);
    float vsum = 0.f;
#pragma unroll
    for (int i = 0; i < 6; ++i) { float d = vals[i] - mean; vsum += d * d; }
#pragma unroll
    for (int o = 32; o; o >>= 1) vsum += __shfl_xor(vsum, o);
    const float rstd = rsqrtf(vsum * (1.f / 384.f) + EPSLN);
#pragma unroll
    for (int i = 0; i < 6; ++i) {
        int c = lane + i * 64;
        float r = base[t * CDIM + c] + (vals[i] - mean) * rstd * g[c] + bta[c];
        outp[t * CDIM + c] = r;
        if (outb) outb[t * CDIM + c] = __float2bfloat16(r);
    }
}

extern "C" void kernel_launch(void* const* d_in, const int* in_sizes, int n_in,
                              void* d_out, int out_size, void* d_ws, size_t ws_size,
                              hipStream_t stream)
{
    const float* x      = (const float*)d_in[0];
    const float* qkv_w  = (const float*)d_in[1];
    const float* qkv_b  = (const float*)d_in[2];
    const float* proj_w = (const float*)d_in[3];
    const float* proj_b = (const float*)d_in[4];
    const float* rpb    = (const float*)d_in[5];
    const float* ln1_g  = (const float*)d_in[6];
    const float* ln1_b  = (const float*)d_in[7];
    const float* fc1_w  = (const float*)d_in[8];
    const float* fc1_b  = (const float*)d_in[9];
    const float* fc2_w  = (const float*)d_in[10];
    const float* fc2_b  = (const float*)d_in[11];
    const float* ln2_g  = (const float*)d_in[12];
    const float* ln2_b  = (const float*)d_in[13];
    const float* amask  = (const float*)d_in[14];
    const int*   relidx = (const int*)d_in[15];
    float* out = (float*)d_out;
    char*  ws  = (char*)d_ws;

    // workspace layout (peak 347,996,160 B)
    bf16*  wq   = (bf16*) (ws + 0L);
    bf16*  wp   = (bf16*) (ws + 884736L);
    bf16*  w1   = (bf16*) (ws + 1179648L);
    bf16*  w2   = (bf16*) (ws + 2359296L);
    float* tbl  = (float*)(ws + 3538944L);      // 12,582,912
    bf16*  xw   = (bf16*) (ws + 16121856L);     // 77,070,336  (dead after QK/V)
    bf16*  qkb  = (bf16*) (ws + 93192192L);     // 154,140,672 q,k (dead after attn)
    bf16*  vTb  = (bf16*) (ws + 247332864L);    // 100,663,296 v^T (dead after attn)
    bf16*  attn_o = (bf16*)(ws + 16121856L);    // reuses xw (dead after proj)
    bf16*  Pbuf = (bf16*) (ws + 93192192L);     // reuses qk (dead after LN1)
    bf16*  x1b  = (bf16*) (ws + 170262528L);    // reuses qk (dead after FC1s)
    bf16*  H1   = (bf16*) (ws + 247332864L);    // reuses vT (per FFN chunk)
    bf16*  Ybuf = (bf16*) (ws + 93192192L);     // reuses Pbuf (after LN1)

    dim3 blk(256);

    cvt_k<<<dim3((3*CDIM*CDIM + 255)/256), blk, 0, stream>>>(qkv_w, wq, 3*CDIM*CDIM);
    cvt_k<<<dim3((CDIM*CDIM + 255)/256), blk, 0, stream>>>(proj_w, wp, CDIM*CDIM);
    cvt_k<<<dim3((HIDD*CDIM + 255)/256), blk, 0, stream>>>(fc1_w, w1, HIDD*CDIM);
    cvt_k<<<dim3((CDIM*HIDD + 255)/256), blk, 0, stream>>>(fc2_w, w2, CDIM*HIDD);
    tbl_k<<<dim3(64*12*64*64/256), blk, 0, stream>>>(rpb, relidx, amask, tbl);
    gather_k<<<dim3(MROWS * 96 / 256), blk, 0, stream>>>(x, xw);

    // 1a. Q,K projection (rows 0..767 of qkv_w)   grid = 784*6
    mgemm_k<M_QK, CDIM, 6><<<dim3((MROWS/128)*6), blk, 0, stream>>>(
        xw, wq, qkv_b, (void*)qkb);
    // 1b. V projection -> transposed [w][h][d][64]  grid = 784*3
    mgemm_k<M_V, CDIM, 3><<<dim3((MROWS/128)*3), blk, 0, stream>>>(
        xw, wq + (long)2*CDIM*CDIM, qkv_b + 2*CDIM, (void*)vTb);

    // 2. MFMA windowed attention
    mattn_k<<<dim3(NWTOT * NHEAD / 4), blk, 0, stream>>>(qkb, vTb, tbl, attn_o);

    // 3. output projection (fused window-reverse scatter)  grid = 784*3
    mgemm_k<M_PROJ, CDIM, 3><<<dim3((MROWS/128)*3), blk, 0, stream>>>(
        attn_o, wp, proj_b, (void*)Pbuf);

    // 4. x1 = x + LN1(P) -> d_out fp32 + bf16 copy
    ln_add_k<<<dim3(MROWS/4), blk, 0, stream>>>(Pbuf, x, ln1_g, ln1_b, out, x1b);

    // 5/6. FFN in four M-chunks (H1 chunk fits freed vT region)
    for (int c = 0; c < 4; ++c) {
        const bf16* a1 = x1b + (long)c * MQ * CDIM;
        bf16* yc = Ybuf + (long)c * MQ * CDIM;
        mgemm_k<M_FC1, CDIM, 12><<<dim3((MQ/128)*12), blk, 0, stream>>>(
            a1, w1, fc1_b, (void*)H1);
        mgemm_k<M_FC2, HIDD, 3><<<dim3((MQ/128)*3), blk, 0, stream>>>(
            H1, w2, fc2_b, (void*)yc);
    }

    // 7. out = x1 + LN2(y)  (in-place)
    ln_add_k<<<dim3(MROWS/4), blk, 0, stream>>>(Ybuf, out, ln2_g, ln2_b, out, nullptr);
}

// Round 7
// 1092.309 us; speedup vs baseline: 1.2589x; 1.0408x over previous
//
#include <hip/hip_runtime.h>
#include <hip/hip_bf16.h>
#include <math.h>

typedef __hip_bfloat16 bf16;
typedef __bf16 bf16x8 __attribute__((ext_vector_type(8)));
typedef float f32x4 __attribute__((ext_vector_type(4)));

#define HH 56
#define WW 56
#define WSZ 7
#define SSH 3
#define NHEAD 12
#define CDIM 384
#define BBATCH 32
#define NTOK 49
#define NWIN 64
#define HIDD 1536
#define HD 32
#define NWTOT (BBATCH*NWIN)       /* 2048 windows */
#define MROWS (NWTOT*NTOK)        /* 100352 rows */
#define MHALF (MROWS/2)           /* 50176 */
#define LTOT (HH*WW)
#define EPSLN 1e-5f
#define QSCALE 0.17677669529663687f
#define NEGBIG -1e30f

enum { M_QK = 0, M_V = 1, M_FC1 = 2 };

__device__ __forceinline__ void gload16(const void* g, void* l) {
    __builtin_amdgcn_global_load_lds(
        (const __attribute__((address_space(1))) void*)g,
        (__attribute__((address_space(3))) void*)l, 16, 0, 0);
}

__device__ __forceinline__ unsigned short bfbits(float v) {
    bf16 b = __float2bfloat16(v);
    return *reinterpret_cast<unsigned short*>(&b);
}

__device__ __forceinline__ int xcd_swz(int orig, int nwg) {
    const int q = nwg >> 3, r = nwg & 7;
    const int xcd = orig & 7, loc = orig >> 3;
    return (xcd < r ? xcd * (q + 1) : r * (q + 1) + (xcd - r) * q) + loc;
}

// ---------------------------------------------------------------------------
__global__ __launch_bounds__(256) void cvt_k(const float* __restrict__ src,
                                             bf16* __restrict__ dst, int n) {
    int i = blockIdx.x * 256 + threadIdx.x;
    if (i < n) dst[i] = __float2bfloat16(src[i]);
}

// bias+mask table: tbl[wi][h][n][m(pad64)] ; m>=49 -> -1e30 (softmax automask)
__global__ __launch_bounds__(256)
void tbl_k(const float* __restrict__ rpb, const int* __restrict__ relidx,
           const float* __restrict__ amask, float* __restrict__ tbl) {
    int idx = blockIdx.x * 256 + threadIdx.x;   // 64*12*64*64
    int m = idx & 63, n = (idx >> 6) & 63;
    int h = (idx >> 12) % NHEAD, wi = idx / (64 * 64 * NHEAD);
    float v;
    if (m >= NTOK) v = NEGBIG;
    else if (n >= NTOK) v = 0.f;
    else v = rpb[relidx[n * NTOK + m] * NHEAD + h] + amask[((long)wi * NTOK + n) * NTOK + m];
    tbl[idx] = v;
}

// x [B][L][C] fp32 -> xw [MROWS][C] bf16 with cyclic shift + window partition
__global__ __launch_bounds__(256) void gather_k(const float* __restrict__ x,
                                                bf16* __restrict__ xw) {
    int idx = blockIdx.x * 256 + threadIdx.x;
    int rr = idx / 96, c4 = (idx % 96) * 4;
    int w = rr / 49, ti = rr % 49;
    int b = w >> 6, wi = w & 63;
    int hy = (wi >> 3) * 7 + ti / 7;
    int hx = (wi & 7) * 7 + ti % 7;
    int sh = hy + SSH; if (sh >= HH) sh -= HH;
    int sw = hx + SSH; if (sw >= WW) sw -= WW;
    float4 v = *(const float4*)&x[((long)b * LTOT + sh * WW + sw) * CDIM + c4];
    bf16* o = &xw[(long)rr * CDIM + c4];
    o[0] = __float2bfloat16(v.x); o[1] = __float2bfloat16(v.y);
    o[2] = __float2bfloat16(v.z); o[3] = __float2bfloat16(v.w);
}

// ---------------------------------------------------------------------------
// MFMA GEMM (128x128, BK=64, 4 waves, dbuf counted-vmcnt, T2 swizzle, XCD
// m-major swizzle). M_QK/M_FC1 SWAP (C^T frags, ushort4 along n); M_V normal.
// ---------------------------------------------------------------------------
template<int MODE, int KDIM, int NTN>
__global__ __launch_bounds__(256)
void mgemm_k(const bf16* __restrict__ A, const bf16* __restrict__ Wt,
             const float* __restrict__ bias, void* __restrict__ Outp)
{
    constexpr bool SWAP = (MODE != M_V);
    __shared__ bf16 As[2][128 * 64];
    __shared__ bf16 Bs[2][128 * 64];
    const int tid = threadIdx.x;
    const int wid = tid >> 6, lane = tid & 63;

    const int gid = xcd_swz(blockIdx.x, gridDim.x);
    const int m0 = (gid / NTN) * 128;
    const int n0 = (gid % NTN) * 128;

    const int srow = lane >> 3, sseg = lane & 7;
    const int swseg = sseg ^ (srow & 7);
    const bf16* Ag = A + (long)(m0 + wid * 32 + srow) * KDIM + swseg * 8;
    const bf16* Wg = Wt + (long)(n0 + wid * 32 + srow) * KDIM + swseg * 8;

    const int wr = (wid >> 1) * 64, wc = (wid & 1) * 64;
    const int l15 = lane & 15, g4 = lane >> 4;

    f32x4 acc[4][4] = {};

    auto STAGE = [&](int b, int t) {
#pragma unroll
        for (int i = 0; i < 4; ++i) {
            gload16(Ag + (long)(i * 8) * KDIM + t * 64, &As[b][(wid * 32 + i * 8) * 64]);
            gload16(Wg + (long)(i * 8) * KDIM + t * 64, &Bs[b][(wid * 32 + i * 8) * 64]);
        }
    };

    const int nt = KDIM / 64;
    STAGE(0, 0);
    STAGE(1, 1);
    asm volatile("s_waitcnt vmcnt(8)" ::: "memory");
    __builtin_amdgcn_s_barrier();

    int buf = 0;
    for (int t = 0; t < nt; ++t) {
        bf16x8 af[2][4], bfr[2][4];
#pragma unroll
        for (int kk = 0; kk < 2; ++kk)
#pragma unroll
            for (int i = 0; i < 4; ++i) {
                const int ra = wr + i * 16 + l15;
                const int rb = wc + i * 16 + l15;
                const int sa = (4 * kk + g4) ^ (ra & 7);
                const int sb = (4 * kk + g4) ^ (rb & 7);
                af[kk][i]  = *(const bf16x8*)&As[buf][ra * 64 + sa * 8];
                bfr[kk][i] = *(const bf16x8*)&Bs[buf][rb * 64 + sb * 8];
            }
        __builtin_amdgcn_sched_barrier(0);
        asm volatile("s_waitcnt lgkmcnt(0)" ::: "memory");
        __builtin_amdgcn_sched_barrier(0);
        __builtin_amdgcn_s_barrier();
        if (t + 2 < nt) STAGE(buf, t + 2);
#pragma unroll
        for (int kk = 0; kk < 2; ++kk)
#pragma unroll
            for (int mi = 0; mi < 4; ++mi)
#pragma unroll
                for (int ni = 0; ni < 4; ++ni) {
                    if (SWAP)
                        acc[ni][mi] = __builtin_amdgcn_mfma_f32_16x16x32_bf16(
                            bfr[kk][ni], af[kk][mi], acc[ni][mi], 0, 0, 0);
                    else
                        acc[mi][ni] = __builtin_amdgcn_mfma_f32_16x16x32_bf16(
                            af[kk][mi], bfr[kk][ni], acc[mi][ni], 0, 0, 0);
                }
        if (t + 2 < nt) { asm volatile("s_waitcnt vmcnt(8)" ::: "memory"); }
        else            { asm volatile("s_waitcnt vmcnt(0)" ::: "memory"); }
        __builtin_amdgcn_s_barrier();
        buf ^= 1;
    }

    // ---------------- epilogue ----------------
    if (MODE == M_V) {
        // acc[mi][ni][j]: m = m0+wr+mi*16+g4*4+j (ti dir), n = n0+wc+ni*16+l15
#pragma unroll
        for (int mi = 0; mi < 4; ++mi) {
            const int mb = m0 + wr + mi * 16 + g4 * 4;
            const int wv_ = mb / 49, ti0 = mb - wv_ * 49;
#pragma unroll
            for (int ni = 0; ni < 4; ++ni) {
                const int n = n0 + wc + ni * 16 + l15;     // h*32+d
                const int h = n >> 5, d = n & 31;
                const float bn = bias[n];
                float v4[4];
#pragma unroll
                for (int j = 0; j < 4; ++j) v4[j] = acc[mi][ni][j] + bn;
                if (ti0 <= 45) {
                    ushort4 u = { bfbits(v4[0]), bfbits(v4[1]), bfbits(v4[2]), bfbits(v4[3]) };
                    *(ushort4*)&((bf16*)Outp)[(((long)wv_ * NHEAD + h) * HD + d) * 64 + ti0] = u;
                } else {
#pragma unroll
                    for (int j = 0; j < 4; ++j) {
                        const int m = mb + j;
                        const int w2 = m / 49, ti = m - w2 * 49;
                        ((bf16*)Outp)[(((long)w2 * NHEAD + h) * HD + d) * 64 + ti]
                            = __float2bfloat16(v4[j]);
                    }
                }
            }
        }
    } else {
        // acc[ni][mi][j]: n = n0+wc+ni*16+g4*4+j, m = m0+wr+mi*16+l15
        long rowbase[4];
        int wq_[4], ti_[4];
#pragma unroll
        for (int mi = 0; mi < 4; ++mi) {
            const int m = m0 + wr + mi * 16 + l15;
            if (MODE == M_QK) { wq_[mi] = m / 49; ti_[mi] = m - wq_[mi] * 49; }
            else rowbase[mi] = (long)m * HIDD;
        }
#pragma unroll
        for (int ni = 0; ni < 4; ++ni) {
            const int nb = n0 + wc + ni * 16 + g4 * 4;
            const float4 bn = *(const float4*)&bias[nb];
            const float bb[4] = { bn.x, bn.y, bn.z, bn.w };
#pragma unroll
            for (int mi = 0; mi < 4; ++mi) {
                float v4[4];
#pragma unroll
                for (int j = 0; j < 4; ++j) v4[j] = acc[ni][mi][j] + bb[j];
                if (MODE == M_FC1) {
#pragma unroll
                    for (int j = 0; j < 4; ++j)
                        v4[j] = 0.5f * v4[j] * (1.0f + erff(v4[j] * 0.70710678118654752f));
                } else {
                    if (nb < CDIM) {
#pragma unroll
                        for (int j = 0; j < 4; ++j) v4[j] *= QSCALE;
                    }
                }
                ushort4 u = { bfbits(v4[0]), bfbits(v4[1]), bfbits(v4[2]), bfbits(v4[3]) };
                if (MODE == M_QK) {
                    const int which = nb >= CDIM;
                    const int hb = (nb - which * CDIM) >> 5, d0 = nb & 31;
                    *(ushort4*)&((bf16*)Outp)[
                        ((((long)wq_[mi] * 2 + which) * NHEAD + hb) * NTOK + ti_[mi]) * HD + d0] = u;
                } else {
                    *(ushort4*)&((bf16*)Outp)[rowbase[mi] + nb] = u;
                }
            }
        }
    }
}

// ---------------------------------------------------------------------------
// Fused GEMM(BMx384xK) + row-LayerNorm + residual-add epilogue.
// 512 thr = 8 waves (2M x 4N), wave = 64x96 (4x6 frags, SWAP C^T layout).
// outp[t] = base[t] + LN(A@W^T + bias)[t]*g + b  (fp32 float4 stores);
// SCATTER: t = window-reverse(m) (PROJ+LN1) and also writes bf16 copy.
// ---------------------------------------------------------------------------
template<int KDIM, bool SCATTER>
__global__ __launch_bounds__(512, 2)
void gemm_ln_k(const bf16* __restrict__ A, const bf16* __restrict__ Wt,
               const float* __restrict__ bias, const float* __restrict__ base,
               const float* __restrict__ lng, const float* __restrict__ lnb,
               float* __restrict__ outp, bf16* __restrict__ outb)
{
    __shared__ bf16 As[2][128 * 64];
    __shared__ bf16 Bs[2][384 * 64];
    const int tid = threadIdx.x;
    const int wid = tid >> 6, lane = tid & 63;

    const int m0 = xcd_swz(blockIdx.x, gridDim.x) * 128;

    const int srow = lane >> 3, sseg = lane & 7;
    const int swseg = sseg ^ (srow & 7);
    const bf16* Ag = A + (long)(m0 + wid * 16 + srow) * KDIM + swseg * 8;
    const bf16* Wg = Wt + (long)(wid * 48 + srow) * KDIM + swseg * 8;

    const int wr = (wid >> 2) * 64, wc = (wid & 3) * 96;
    const int l15 = lane & 15, g4 = lane >> 4;

    f32x4 acc[6][4] = {};   // [ni][mi], SWAP layout: n = wc+ni*16+g4*4+j, m = wr+mi*16+l15

    auto STAGE = [&](int b, int t) {
#pragma unroll
        for (int i = 0; i < 2; ++i)
            gload16(Ag + (long)(i * 8) * KDIM + t * 64, &As[b][(wid * 16 + i * 8) * 64]);
#pragma unroll
        for (int i = 0; i < 6; ++i)
            gload16(Wg + (long)(i * 8) * KDIM + t * 64, &Bs[b][(wid * 48 + i * 8) * 64]);
    };

    const int nt = KDIM / 64;
    STAGE(0, 0);
    STAGE(1, 1);
    asm volatile("s_waitcnt vmcnt(8)" ::: "memory");
    __builtin_amdgcn_s_barrier();

    int buf = 0;
    for (int t = 0; t < nt; ++t) {
        bf16x8 af[2][4], bfr[2][6];
#pragma unroll
        for (int kk = 0; kk < 2; ++kk) {
#pragma unroll
            for (int i = 0; i < 4; ++i) {
                const int ra = wr + i * 16 + l15;
                const int sa = (4 * kk + g4) ^ (ra & 7);
                af[kk][i] = *(const bf16x8*)&As[buf][ra * 64 + sa * 8];
            }
#pragma unroll
            for (int i = 0; i < 6; ++i) {
                const int rb = wc + i * 16 + l15;
                const int sb = (4 * kk + g4) ^ (rb & 7);
                bfr[kk][i] = *(const bf16x8*)&Bs[buf][rb * 64 + sb * 8];
            }
        }
        __builtin_amdgcn_sched_barrier(0);
        asm volatile("s_waitcnt lgkmcnt(0)" ::: "memory");
        __builtin_amdgcn_sched_barrier(0);
        __builtin_amdgcn_s_barrier();
        if (t + 2 < nt) STAGE(buf, t + 2);
#pragma unroll
        for (int kk = 0; kk < 2; ++kk)
#pragma unroll
            for (int ni = 0; ni < 6; ++ni)
#pragma unroll
                for (int mi = 0; mi < 4; ++mi)
                    acc[ni][mi] = __builtin_amdgcn_mfma_f32_16x16x32_bf16(
                        bfr[kk][ni], af[kk][mi], acc[ni][mi], 0, 0, 0);
        if (t + 2 < nt) { asm volatile("s_waitcnt vmcnt(8)" ::: "memory"); }
        else            { asm volatile("s_waitcnt vmcnt(0)" ::: "memory"); }
        __builtin_amdgcn_s_barrier();
        buf ^= 1;
    }

    // ---- epilogue: bias add, row partial sums, cross-wave LN reduce ----
    float psum[4] = {}, psq[4] = {};
#pragma unroll
    for (int ni = 0; ni < 6; ++ni) {
        const int nb = wc + ni * 16 + g4 * 4;
        const float4 bn = *(const float4*)&bias[nb];
        const float bb[4] = { bn.x, bn.y, bn.z, bn.w };
#pragma unroll
        for (int mi = 0; mi < 4; ++mi)
#pragma unroll
            for (int j = 0; j < 4; ++j) {
                float v = acc[ni][mi][j] + bb[j];
                acc[ni][mi][j] = v;
                psum[mi] += v; psq[mi] += v * v;
            }
    }
#pragma unroll
    for (int mi = 0; mi < 4; ++mi) {
        psum[mi] += __shfl_xor(psum[mi], 16); psum[mi] += __shfl_xor(psum[mi], 32);
        psq[mi]  += __shfl_xor(psq[mi], 16);  psq[mi]  += __shfl_xor(psq[mi], 32);
    }
    float* lnp = (float*)&As[0][0];          // [2][4 wc][128 rows] = 4 KB
    const int wcid = wid & 3;
    if (g4 == 0) {
#pragma unroll
        for (int mi = 0; mi < 4; ++mi) {
            const int rl = wr + mi * 16 + l15;
            lnp[wcid * 128 + rl] = psum[mi];
            lnp[512 + wcid * 128 + rl] = psq[mi];
        }
    }
    __syncthreads();

#pragma unroll
    for (int mi = 0; mi < 4; ++mi) {
        const int rl = wr + mi * 16 + l15;
        const float s  = lnp[rl] + lnp[128 + rl] + lnp[256 + rl] + lnp[384 + rl];
        const float sq = lnp[512 + rl] + lnp[640 + rl] + lnp[768 + rl] + lnp[896 + rl];
        const float mean = s * (1.f / 384.f);
        const float rstd = rsqrtf(sq * (1.f / 384.f) - mean * mean + EPSLN);

        const int m = m0 + rl;
        long tok;
        if (SCATTER) {
            int w = m / 49, ti = m - w * 49;
            int b = w >> 6, wi = w & 63;
            int hy = (wi >> 3) * 7 + ti / 7;
            int hx = (wi & 7) * 7 + ti % 7;
            int dh = hy + SSH; if (dh >= HH) dh -= HH;
            int dw = hx + SSH; if (dw >= WW) dw -= WW;
            tok = (long)b * LTOT + dh * WW + dw;
        } else {
            tok = m;
        }
#pragma unroll
        for (int ni = 0; ni < 6; ++ni) {
            const int c = wc + ni * 16 + g4 * 4;
            const float4 gv = *(const float4*)&lng[c];
            const float4 bv = *(const float4*)&lnb[c];
            const float4 xv = *(const float4*)&base[tok * CDIM + c];
            float4 r;
            r.x = xv.x + (acc[ni][mi][0] - mean) * rstd * gv.x + bv.x;
            r.y = xv.y + (acc[ni][mi][1] - mean) * rstd * gv.y + bv.y;
            r.z = xv.z + (acc[ni][mi][2] - mean) * rstd * gv.z + bv.z;
            r.w = xv.w + (acc[ni][mi][3] - mean) * rstd * gv.w + bv.w;
            *(float4*)&outp[tok * CDIM + c] = r;
            if (SCATTER) {
                ushort4 u = { bfbits(r.x), bfbits(r.y), bfbits(r.z), bfbits(r.w) };
                *(ushort4*)&outb[tok * CDIM + c] = u;
            }
        }
    }
}

// ---------------------------------------------------------------------------
// MFMA attention: 4 waves/block, each wave = one (window, head). Unchanged.
// ---------------------------------------------------------------------------
__global__ __launch_bounds__(256)
void mattn_k(const bf16* __restrict__ qk, const bf16* __restrict__ vT,
             const float* __restrict__ tbl, bf16* __restrict__ attn_out)
{
    __shared__ bf16 Plds[4][64 * 72];
    const int tid = threadIdx.x, wid = tid >> 6, lane = tid & 63;
    const int t = blockIdx.x * 4 + wid;
    const int w = t / NHEAD, h = t % NHEAD, wi = w & 63;
    const int l15 = lane & 15, g = lane >> 4;
    const bf16* qb = qk + ((long)(w * 2 + 0) * NHEAD + h) * (NTOK * HD);
    const bf16* kb = qk + ((long)(w * 2 + 1) * NHEAD + h) * (NTOK * HD);
    const bf16* vt = vT + ((long)w * NHEAD + h) * (HD * 64);
    const float* Tb = tbl + (long)(wi * NHEAD + h) * 64 * 64;
    char* Pw = (char*)&Plds[wid][0];

    bf16x8 kf[4], qf[4];
#pragma unroll
    for (int i = 0; i < 4; ++i) {
        kf[i] = *(const bf16x8*)&kb[(16 * i + l15) * HD + 8 * g];
        qf[i] = *(const bf16x8*)&qb[(16 * i + l15) * HD + 8 * g];
    }
    f32x4 s[4][4] = {};
#pragma unroll
    for (int mi = 0; mi < 4; ++mi)
#pragma unroll
        for (int ni = 0; ni < 4; ++ni)
            s[mi][ni] = __builtin_amdgcn_mfma_f32_16x16x32_bf16(
                kf[mi], qf[ni], s[mi][ni], 0, 0, 0);

#pragma unroll
    for (int ni = 0; ni < 4; ++ni) {
        const int n = 16 * ni + l15;
#pragma unroll
        for (int mi = 0; mi < 4; ++mi) {
            float4 tv = *(const float4*)&Tb[(long)n * 64 + 16 * mi + 4 * g];
            s[mi][ni][0] += tv.x; s[mi][ni][1] += tv.y;
            s[mi][ni][2] += tv.z; s[mi][ni][3] += tv.w;
        }
        float mx = NEGBIG;
#pragma unroll
        for (int mi = 0; mi < 4; ++mi)
#pragma unroll
            for (int j = 0; j < 4; ++j) mx = fmaxf(mx, s[mi][ni][j]);
        mx = fmaxf(mx, __shfl_xor(mx, 16));
        mx = fmaxf(mx, __shfl_xor(mx, 32));
        float sum = 0.f;
#pragma unroll
        for (int mi = 0; mi < 4; ++mi)
#pragma unroll
            for (int j = 0; j < 4; ++j) {
                float e = expf(s[mi][ni][j] - mx);
                s[mi][ni][j] = e; sum += e;
            }
        sum += __shfl_xor(sum, 16);
        sum += __shfl_xor(sum, 32);
        const float r = 1.0f / sum;
#pragma unroll
        for (int mi = 0; mi < 4; ++mi) {
            ushort4 u;
            u.x = bfbits(s[mi][ni][0] * r);
            u.y = bfbits(s[mi][ni][1] * r);
            u.z = bfbits(s[mi][ni][2] * r);
            u.w = bfbits(s[mi][ni][3] * r);
            *(ushort4*)(Pw + (long)n * 144 + (16 * mi + 4 * g) * 2) = u;
        }
    }

    f32x4 o[4][2] = {};
#pragma unroll
    for (int kk = 0; kk < 2; ++kk) {
        bf16x8 vf[2];
        vf[0] = *(const bf16x8*)&vt[(long)(l15) * 64 + 32 * kk + 8 * g];
        vf[1] = *(const bf16x8*)&vt[(long)(16 + l15) * 64 + 32 * kk + 8 * g];
#pragma unroll
        for (int rt = 0; rt < 4; ++rt) {
            bf16x8 pf = *(const bf16x8*)(Pw + (long)(16 * rt + l15) * 144 + (32 * kk + 8 * g) * 2);
            o[rt][0] = __builtin_amdgcn_mfma_f32_16x16x32_bf16(pf, vf[0], o[rt][0], 0, 0, 0);
            o[rt][1] = __builtin_amdgcn_mfma_f32_16x16x32_bf16(pf, vf[1], o[rt][1], 0, 0, 0);
        }
    }

#pragma unroll
    for (int rt = 0; rt < 4; ++rt)
#pragma unroll
        for (int dt = 0; dt < 2; ++dt)
#pragma unroll
            for (int j = 0; j < 4; ++j) {
                int n = 16 * rt + 4 * g + j;
                if (n < NTOK)
                    attn_out[((long)w * NTOK + n) * CDIM + h * HD + 16 * dt + l15]
                        = __float2bfloat16(o[rt][dt][j]);
            }
}

extern "C" void kernel_launch(void* const* d_in, const int* in_sizes, int n_in,
                              void* d_out, int out_size, void* d_ws, size_t ws_size,
                              hipStream_t stream)
{
    const float* x      = (const float*)d_in[0];
    const float* qkv_w  = (const float*)d_in[1];
    const float* qkv_b  = (const float*)d_in[2];
    const float* proj_w = (const float*)d_in[3];
    const float* proj_b = (const float*)d_in[4];
    const float* rpb    = (const float*)d_in[5];
    const float* ln1_g  = (const float*)d_in[6];
    const float* ln1_b  = (const float*)d_in[7];
    const float* fc1_w  = (const float*)d_in[8];
    const float* fc1_b  = (const float*)d_in[9];
    const float* fc2_w  = (const float*)d_in[10];
    const float* fc2_b  = (const float*)d_in[11];
    const float* ln2_g  = (const float*)d_in[12];
    const float* ln2_b  = (const float*)d_in[13];
    const float* amask  = (const float*)d_in[14];
    const int*   relidx = (const int*)d_in[15];
    float* out = (float*)d_out;
    char*  ws  = (char*)d_ws;

    // workspace layout (peak 347,996,160 B; proven available)
    bf16*  wq   = (bf16*) (ws + 0L);            //   884,736
    bf16*  wp   = (bf16*) (ws + 884736L);       //   294,912
    bf16*  w1   = (bf16*) (ws + 1179648L);      // 1,179,648
    bf16*  w2   = (bf16*) (ws + 2359296L);      // 1,179,648
    float* tbl  = (float*)(ws + 3538944L);      // 12,582,912 (dead after mattn)
    bf16*  xw   = (bf16*) (ws + 16121856L);     // 77,070,336 (dead after QK/V)
    bf16*  qkb  = (bf16*) (ws + 93192192L);     // 154,140,672 (dead after mattn)
    bf16*  vTb  = (bf16*) (ws + 247332864L);    // 100,663,296 (dead after mattn)
    bf16*  attn_o = (bf16*)(ws + 16121856L);    // reuses xw (dead after proj_ln)
    bf16*  x1b  = (bf16*) (ws + 93192192L);     // reuses qkb (written by proj_ln)
    bf16*  H1   = (bf16*) (ws + 170262528L);    // 154,140,672 per FFN half

    dim3 b256(256), b512(512);

    cvt_k<<<dim3((3*CDIM*CDIM + 255)/256), b256, 0, stream>>>(qkv_w, wq, 3*CDIM*CDIM);
    cvt_k<<<dim3((CDIM*CDIM + 255)/256), b256, 0, stream>>>(proj_w, wp, CDIM*CDIM);
    cvt_k<<<dim3((HIDD*CDIM + 255)/256), b256, 0, stream>>>(fc1_w, w1, HIDD*CDIM);
    cvt_k<<<dim3((CDIM*HIDD + 255)/256), b256, 0, stream>>>(fc2_w, w2, CDIM*HIDD);
    tbl_k<<<dim3(64*12*64*64/256), b256, 0, stream>>>(rpb, relidx, amask, tbl);
    gather_k<<<dim3(MROWS * 96 / 256), b256, 0, stream>>>(x, xw);

    // 1a. Q,K projection   grid = 784*6
    mgemm_k<M_QK, CDIM, 6><<<dim3((MROWS/128)*6), b256, 0, stream>>>(
        xw, wq, qkv_b, (void*)qkb);
    // 1b. V projection -> transposed [w][h][d][64]  grid = 784*3
    mgemm_k<M_V, CDIM, 3><<<dim3((MROWS/128)*3), b256, 0, stream>>>(
        xw, wq + (long)2*CDIM*CDIM, qkv_b + 2*CDIM, (void*)vTb);

    // 2. MFMA windowed attention
    mattn_k<<<dim3(NWTOT * NHEAD / 4), b256, 0, stream>>>(qkb, vTb, tbl, attn_o);

    // 3. fused PROJ + LN1: out = x + LN(attn@Wp+b), + bf16 copy x1b
    gemm_ln_k<CDIM, true><<<dim3(MROWS/128), b512, 0, stream>>>(
        attn_o, wp, proj_b, x, ln1_g, ln1_b, out, x1b);

    // 4/5. FFN in two M-halves; FC2 fused with LN2 (in-place on d_out)
    for (int c = 0; c < 2; ++c) {
        const long off = (long)c * MHALF * CDIM;
        mgemm_k<M_FC1, CDIM, 12><<<dim3((MHALF/128)*12), b256, 0, stream>>>(
            x1b + off, w1, fc1_b, (void*)H1);
        gemm_ln_k<HIDD, false><<<dim3(MHALF/128), b512, 0, stream>>>(
            H1, w2, fc2_b, out + off, ln2_g, ln2_b, out + off, nullptr);
    }
}